// Round 9
// baseline (478.211 us; speedup 1.0000x reference)
//
#include <hip/hip_runtime.h>
#include <math.h>

#define F_IN 128
#define D 256
#define H 4
#define C 64
#define NEG_SLOPE 0.2f

typedef __attribute__((ext_vector_type(8))) unsigned short ushort8;
typedef __attribute__((ext_vector_type(8))) short short8;
typedef __attribute__((ext_vector_type(4))) float floatx4;

// ---------------- helpers ----------------
__device__ __forceinline__ float leaky(float x) {
  return (x >= 0.f) ? x : NEG_SLOPE * x;
}
__device__ __forceinline__ unsigned short f2bf(float f) {  // round-nearest-even
  unsigned u = __float_as_uint(f);
  return (unsigned short)((u + 0x7fffu + ((u >> 16) & 1u)) >> 16);
}
__device__ __forceinline__ float bf2f(unsigned short s) {
  return __uint_as_float((unsigned)s << 16);
}
__device__ __forceinline__ float waveReduceSum(float v) {
#pragma unroll
  for (int off = 32; off > 0; off >>= 1) v += __shfl_xor(v, off, 64);
  return v;
}

// ---------------- bf16 MFMA GEMM: C[M,Ncol] = A[M,K] @ Bt[Ncol,K]^T ----------------
// A: row-major, fp32 (AFP32, converted during staging) or bf16. Bt: bf16 k-contig.
// 128x128 tile, k-step 32. LDS rows padded to 40 ushorts (80 B = 20 banks,
// coprime with 32) to break the 8-way fragment-read bank conflict.
template <bool AFP32, bool BF16OUT>
__global__ __launch_bounds__(256) void gemm_mfma(
    const void* __restrict__ Ain, const unsigned short* __restrict__ Bt,
    void* __restrict__ Cout, int M, int K, int Ncol) {
  __shared__ unsigned short Alds[128][40];
  __shared__ unsigned short Blds[128][40];

  const int t = threadIdx.x;
  const int w = t >> 6;   // wave -> n-quarter
  const int l = t & 63;
  const int bm = blockIdx.x * 128;
  const int bn = blockIdx.y * 128;

  const int m16 = l & 15;  // A-row / B-row / C-col within 16-tile
  const int q = l >> 4;    // quad: k-offset q*8 (frags), C-row q*4+i

  const int sr = t >> 1;
  const int sc = (t & 1) * 2;
  int agr = bm + sr; if (agr >= M) agr = M - 1;
  const int bgr = bn + sr;  // Ncol multiple of 128: no guard

  floatx4 acc[8][2] = {};

  for (int k0 = 0; k0 < K; k0 += 32) {
    if (AFP32) {
      const float* Af = (const float*)Ain;
      float av[16];
      *(float4*)&av[0]  = *(const float4*)&Af[(size_t)agr * K + k0 + sc * 8];
      *(float4*)&av[4]  = *(const float4*)&Af[(size_t)agr * K + k0 + sc * 8 + 4];
      *(float4*)&av[8]  = *(const float4*)&Af[(size_t)agr * K + k0 + (sc + 1) * 8];
      *(float4*)&av[12] = *(const float4*)&Af[(size_t)agr * K + k0 + (sc + 1) * 8 + 4];
      ushort8 a0, a1;
#pragma unroll
      for (int i = 0; i < 8; ++i) { a0[i] = f2bf(av[i]); a1[i] = f2bf(av[8 + i]); }
      *(ushort8*)&Alds[sr][sc * 8] = a0;
      *(ushort8*)&Alds[sr][(sc + 1) * 8] = a1;
    } else {
      const unsigned short* Ab = (const unsigned short*)Ain;
      const ushort8 a0 = *(const ushort8*)&Ab[(size_t)agr * K + k0 + sc * 8];
      const ushort8 a1 = *(const ushort8*)&Ab[(size_t)agr * K + k0 + (sc + 1) * 8];
      *(ushort8*)&Alds[sr][sc * 8] = a0;
      *(ushort8*)&Alds[sr][(sc + 1) * 8] = a1;
    }
    {
      const ushort8 b0 = *(const ushort8*)&Bt[(size_t)bgr * K + k0 + sc * 8];
      const ushort8 b1 = *(const ushort8*)&Bt[(size_t)bgr * K + k0 + (sc + 1) * 8];
      *(ushort8*)&Blds[sr][sc * 8] = b0;
      *(ushort8*)&Blds[sr][(sc + 1) * 8] = b1;
    }
    __syncthreads();

    short8 bf[2];
#pragma unroll
    for (int nt = 0; nt < 2; ++nt)
      bf[nt] = *(const short8*)&Blds[w * 32 + nt * 16 + m16][q * 8];
#pragma unroll
    for (int mt = 0; mt < 8; ++mt) {
      const short8 af = *(const short8*)&Alds[mt * 16 + m16][q * 8];
      acc[mt][0] = __builtin_amdgcn_mfma_f32_16x16x32_bf16(af, bf[0], acc[mt][0], 0, 0, 0);
      acc[mt][1] = __builtin_amdgcn_mfma_f32_16x16x32_bf16(af, bf[1], acc[mt][1], 0, 0, 0);
    }
    __syncthreads();
  }

#pragma unroll
  for (int mt = 0; mt < 8; ++mt)
#pragma unroll
    for (int nt = 0; nt < 2; ++nt) {
      const int col = bn + w * 32 + nt * 16 + m16;
#pragma unroll
      for (int i = 0; i < 4; ++i) {
        const int row = bm + mt * 16 + q * 4 + i;
        if (row < M) {
          if (BF16OUT)
            ((unsigned short*)Cout)[(size_t)row * Ncol + col] = f2bf(acc[mt][nt][i]);
          else
            ((float*)Cout)[(size_t)row * Ncol + col] = acc[mt][nt][i];
        }
      }
    }
}

// ---------------- fused weight prep: W1t[256][128], W2t[256][256], BcT[128][256] ----------------
__global__ void prep_weights(const float* __restrict__ W1, const float* __restrict__ W2,
                             const float* __restrict__ Ws1,
                             unsigned short* __restrict__ W1t,
                             unsigned short* __restrict__ W2t,
                             unsigned short* __restrict__ BcT) {
  const int i = blockIdx.x * 256 + threadIdx.x;
  if (i < 256 * 128) {  // W1t[n][k] = W1[k][n], K=128, Ncol=256
    const int n = i >> 7, k = i & 127;
    W1t[i] = f2bf(W1[(size_t)k * 256 + n]);
  }
  if (i < 256 * 256) {  // W2t[n][k] = W2[k][n]
    const int n = i >> 8, k = i & 255;
    W2t[i] = f2bf(W2[(size_t)k * 256 + n]);
  }
  if (i < 128 * 256) {  // BcT[n][k]: n<64 -> Ws1 P-half, else Q-half
    const int n = i >> 8, k = i & 255;
    const float v = (n < 64) ? Ws1[(size_t)k * 64 + n]
                             : Ws1[(size_t)(k + 256) * 64 + (n - 64)];
    BcT[i] = f2bf(v);
  }
}

// ---------------- attention logits: 8 nodes/block (2 per wave) ----------------
__global__ __launch_bounds__(256) void logits_kernel(
    const unsigned short* __restrict__ hb, const float* __restrict__ a_src,
    const float* __restrict__ a_dst, float* __restrict__ al_src,
    float* __restrict__ al_dst, int N) {
  const int wave = threadIdx.x >> 6;
  const int lane = threadIdx.x & 63;
  const int half = lane >> 5;
  const int l32 = lane & 31;
  const int n = blockIdx.x * 8 + wave * 2 + half;
  if (n >= N) return;
  const int c8 = l32 * 8;
  const ushort8 hv = *(const ushort8*)&hb[(size_t)n * D + c8];
  float as[8], ad[8];
  *(float4*)&as[0] = *(const float4*)&a_src[c8];
  *(float4*)&as[4] = *(const float4*)&a_src[c8 + 4];
  *(float4*)&ad[0] = *(const float4*)&a_dst[c8];
  *(float4*)&ad[4] = *(const float4*)&a_dst[c8 + 4];
  float ps = 0.f, pd = 0.f;
#pragma unroll
  for (int i = 0; i < 8; ++i) {
    const float hf = bf2f(hv[i]);
    ps += hf * as[i];
    pd += hf * ad[i];
  }
  ps += __shfl_xor(ps, 1, 64); pd += __shfl_xor(pd, 1, 64);
  ps += __shfl_xor(ps, 2, 64); pd += __shfl_xor(pd, 2, 64);
  ps += __shfl_xor(ps, 4, 64); pd += __shfl_xor(pd, 4, 64);
  if ((l32 & 7) == 0) {
    const int h = l32 >> 3;
    al_src[n * H + h] = ps;
    al_dst[n * H + h] = pd;
  }
}

// ---------------- CSR build ----------------
__global__ void hist_kernel(const int* __restrict__ ei, int E, int N,
                            int* __restrict__ count) {
  const int e = blockIdx.x * blockDim.x + threadIdx.x;
  if (e >= E + N) return;
  const int d = (e < E) ? ei[E + e] : (e - E);
  atomicAdd(&count[d], 1);
}

__global__ __launch_bounds__(256) void scan_block(const int* __restrict__ in,
                                                  int* __restrict__ out,
                                                  int* __restrict__ blockSums, int n) {
  const int i = blockIdx.x * 256 + threadIdx.x;
  const int lane = threadIdx.x & 63;
  const int wid = threadIdx.x >> 6;
  const int val = (i < n) ? in[i] : 0;
  int incl = val;
#pragma unroll
  for (int off = 1; off < 64; off <<= 1) {
    int m = __shfl_up(incl, off, 64);
    if (lane >= off) incl += m;
  }
  __shared__ int wsum[4], woff[5];
  if (lane == 63) wsum[wid] = incl;
  __syncthreads();
  if (threadIdx.x == 0) {
    int s = 0;
    for (int w = 0; w < 4; ++w) { woff[w] = s; s += wsum[w]; }
    woff[4] = s;
  }
  __syncthreads();
  if (i < n) out[i] = incl - val + woff[wid];
  if (threadIdx.x == 0 && blockSums) blockSums[blockIdx.x] = woff[4];
}

__global__ void scan_add(int* __restrict__ data, const int* __restrict__ blockOff, int n) {
  const int i = blockIdx.x * 256 + threadIdx.x;
  if (i < n) data[i] += blockOff[blockIdx.x];
}

__global__ void scatter_kernel(const int* __restrict__ ei, int E, int N,
                               const int* __restrict__ rowptr,
                               int* __restrict__ fill, int* __restrict__ esrc) {
  const int e = blockIdx.x * blockDim.x + threadIdx.x;
  if (e >= E + N) return;
  int s, d;
  if (e < E) { s = ei[e]; d = ei[E + e]; } else { s = d = e - E; }
  const int pos = rowptr[d] + atomicAdd(&fill[d], 1);
  esrc[pos] = s;
}

// ---------------- fused GAT aggregation: one wave per dst node ----------------
// No max pass (softmax shift-invariant; |logit| O(1), exp safe in fp32).
// Phase 1: lane-per-edge, one random float4 al_src gather (L2-resident),
// all-4-head exp cached in wave-private LDS as walpha[wave][edge][head]
// padded to [64][5]: phase-2 reads hit 4 consecutive words (distinct banks),
// stride-5 phase-1 writes are <=2-way (free). cnt>64 tail recomputes.
__global__ __launch_bounds__(256) void agg_wave_kernel(
    const int* __restrict__ rowptr, const int* __restrict__ count,
    const int* __restrict__ esrc, const float* __restrict__ al_src,
    const float* __restrict__ al_dst, const unsigned short* __restrict__ hb,
    const float* __restrict__ bias, unsigned short* __restrict__ out, int N) {
  const int wave = threadIdx.x >> 6;
  const int d = blockIdx.x * 4 + wave;
  if (d >= N) return;
  const int lane = threadIdx.x & 63;
  const int base = rowptr[d];
  const int cnt = count[d];
  const float4 ald4 = *(const float4*)&al_dst[d * 4];
  const int* __restrict__ es = esrc + base;

  __shared__ float walpha[4][64][5];  // [wave][edge][head(+pad)], wave-private

  // phase 1: un-normalized exp weights + denominators, lane-per-edge
  float s0 = 0.f, s1 = 0.f, s2 = 0.f, s3 = 0.f;
  for (int i = lane; i < cnt; i += 64) {
    const float4 a = *(const float4*)&al_src[es[i] * 4];
    const float e0 = __expf(leaky(a.x + ald4.x));
    const float e1 = __expf(leaky(a.y + ald4.y));
    const float e2 = __expf(leaky(a.z + ald4.z));
    const float e3 = __expf(leaky(a.w + ald4.w));
    s0 += e0; s1 += e1; s2 += e2; s3 += e3;
    if (i < 64) {
      walpha[wave][i][0] = e0;
      walpha[wave][i][1] = e1;
      walpha[wave][i][2] = e2;
      walpha[wave][i][3] = e3;
    }
  }
#pragma unroll
  for (int off = 32; off > 0; off >>= 1) {
    s0 += __shfl_xor(s0, off, 64);
    s1 += __shfl_xor(s1, off, 64);
    s2 += __shfl_xor(s2, off, 64);
    s3 += __shfl_xor(s3, off, 64);
  }
  const float inv4[4] = {1.f / s0, 1.f / s1, 1.f / s2, 1.f / s3};

  // phase 2: half-wave per edge, lane covers 8 channels
  const int half = lane >> 5;
  const int l32 = lane & 31;
  const int c8 = l32 * 8;
  const int ch = l32 >> 3;  // head owning my channels
  const float invB = inv4[ch];
  const float aldB = ((const float*)&ald4)[ch];

  float acc[8] = {};
  for (int j = half; j < cnt; j += 2) {
    const int s = es[j];
    float wgt;
    if (j < 64) {
      wgt = walpha[wave][j][ch];
    } else {  // rare tail: recompute
      const float4 a = *(const float4*)&al_src[s * 4];
      wgt = __expf(leaky(((const float*)&a)[ch] + aldB));
    }
    const float alpha = wgt * invB;
    const ushort8 hv = *(const ushort8*)&hb[(size_t)s * D + c8];
#pragma unroll
    for (int i = 0; i < 8; ++i) acc[i] += bf2f(hv[i]) * alpha;
  }
#pragma unroll
  for (int i = 0; i < 8; ++i) acc[i] += __shfl_xor(acc[i], 32, 64);
  if (half == 0) {
    ushort8 o;
#pragma unroll
    for (int i = 0; i < 8; ++i) {
      const float v = acc[i] + bias[c8 + i];
      o[i] = f2bf((v > 0.f) ? v : expm1f(v));
    }
    *(ushort8*)&out[(size_t)d * D + c8] = o;
  }
}

// ---------------- final scorer ----------------
__global__ __launch_bounds__(256) void score_kernel(
    const int* __restrict__ eli, int EL, const float* __restrict__ PQ,
    const float* __restrict__ bs1, const float* __restrict__ Ws2,
    const float* __restrict__ bs2, float* __restrict__ out) {
  const int e = blockIdx.x * 4 + (threadIdx.x >> 6);
  if (e >= EL) return;
  const int lane = threadIdx.x & 63;
  const int a = eli[e];
  const int b = eli[EL + e];
  float p = PQ[(size_t)a * 128 + lane] + PQ[(size_t)b * 128 + 64 + lane] + bs1[lane];
  p = (p > 0.f) ? p : 0.f;
  const float sum = waveReduceSum(p * Ws2[lane]);
  if (lane == 0) out[e] = sum + bs2[0];
}

// ---------------- launcher ----------------
extern "C" void kernel_launch(void* const* d_in, const int* in_sizes, int n_in,
                              void* d_out, int out_size, void* d_ws, size_t ws_size,
                              hipStream_t stream) {
  const float* x   = (const float*)d_in[0];
  const int*   ei  = (const int*)d_in[1];
  const int*   eli = (const int*)d_in[2];
  const float* W1  = (const float*)d_in[3];
  const float* as1 = (const float*)d_in[4];
  const float* ad1 = (const float*)d_in[5];
  const float* b1  = (const float*)d_in[6];
  const float* W2  = (const float*)d_in[7];
  const float* as2 = (const float*)d_in[8];
  const float* ad2 = (const float*)d_in[9];
  const float* b2  = (const float*)d_in[10];
  const float* Ws1 = (const float*)d_in[11];
  const float* bs1 = (const float*)d_in[12];
  const float* Ws2 = (const float*)d_in[13];
  const float* bs2 = (const float*)d_in[14];

  const int N = in_sizes[0] / F_IN;
  const int E = in_sizes[1] / 2;
  const int EL = in_sizes[2] / 2;
  const int Etot = E + N;

  // ws layout (identical to last-known-good R6 layout)
  unsigned short* hb = (unsigned short*)d_ws;            // N*D bf16
  unsigned short* zb = hb + (size_t)N * D;               // N*D bf16
  unsigned short* W1t = zb + (size_t)N * D;              // 256*128
  unsigned short* W2t = W1t + 256 * 128;                 // 256*256
  unsigned short* BcT = W2t + 256 * 256;                 // 128*256
  float* PQ     = (float*)(BcT + 128 * 256);             // N*128 f32
  float* al_src = PQ + (size_t)N * 128;                  // N*H
  float* al_dst = al_src + (size_t)N * H;                // N*H
  int* count  = (int*)(al_dst + (size_t)N * H);          // N
  int* rowptr = count + N;                               // N
  int* fill   = rowptr + N;                              // N
  int* blockSums = fill + N;                             // 256
  int* blockOff  = blockSums + 256;                      // 256
  int* esrc   = blockOff + 256;                          // Etot

  const int edgeBlocks = (Etot + 255) / 256;
  const int nb = (N + 255) / 256;
  const dim3 gridLayer((N + 127) / 128, D / 128);
  const dim3 gridScore((N + 127) / 128, 1);

  // ---- CSR build (shared by both layers) + weight prep ----
  hipMemsetAsync(count, 0, (size_t)N * sizeof(int), stream);
  hipMemsetAsync(fill, 0, (size_t)N * sizeof(int), stream);
  hist_kernel<<<edgeBlocks, 256, 0, stream>>>(ei, E, N, count);
  scan_block<<<nb, 256, 0, stream>>>(count, rowptr, blockSums, N);
  scan_block<<<1, 256, 0, stream>>>(blockSums, blockOff, nullptr, nb);
  scan_add<<<nb, 256, 0, stream>>>(rowptr, blockOff, N);
  scatter_kernel<<<edgeBlocks, 256, 0, stream>>>(ei, E, N, rowptr, fill, esrc);
  prep_weights<<<256, 256, 0, stream>>>(W1, W2, Ws1, W1t, W2t, BcT);

  // ---- layer 1 (A = x fp32, converted in staging) ----
  gemm_mfma<true, true><<<gridLayer, 256, 0, stream>>>(x, W1t, hb, N, F_IN, D);
  logits_kernel<<<(N + 7) / 8, 256, 0, stream>>>(hb, as1, ad1, al_src, al_dst, N);
  agg_wave_kernel<<<(N + 3) / 4, 256, 0, stream>>>(rowptr, count, esrc, al_src,
                                                   al_dst, hb, b1, zb, N);

  // ---- layer 2 ----
  gemm_mfma<false, true><<<gridLayer, 256, 0, stream>>>(zb, W2t, hb, N, D, D);
  logits_kernel<<<(N + 7) / 8, 256, 0, stream>>>(hb, as2, ad2, al_src, al_dst, N);
  agg_wave_kernel<<<(N + 3) / 4, 256, 0, stream>>>(rowptr, count, esrc, al_src,
                                                   al_dst, hb, b2, zb, N);

  // ---- scorer: PQ = z2 @ BcT^T; per-edge reduce ----
  gemm_mfma<false, false><<<gridScore, 256, 0, stream>>>(zb, BcT, PQ, N, D, 128);
  score_kernel<<<(EL + 3) / 4, 256, 0, stream>>>(eli, EL, PQ, bs1, Ws2, bs2,
                                                 (float*)d_out);
}